// Round 1
// 416.318 us; speedup vs baseline: 1.0074x; 1.0074x over previous
//
#include <hip/hip_runtime.h>

// LinearSpline: per-channel scaled B1-spline lookup.
// x: [16, 64, 256, 256] fp32; coef: [64*129] fp32; scale: [64] fp32; zk: [64] int32.
// GRID = 0.0625 (pow2 -> x/GRID == x*16 exactly), RANGE = 4.0, SIZE = 129 (odd).
//
// Each block handles 4096 contiguous elements -> exactly one channel.
// Fused table entry: tab[k] = { (c[k] - GRID/2)*rs , (c[k+1]-c[k])*rs }
// so the per-element epilogue is a single ds_read_b64 + fmaf.
// Clamp in the *16-scaled domain: clamp(xs,-4,3.9375)*16 == clamp(xs*16,-64,63).
//
// This version removes __syncthreads entirely: the table is WAVE-PRIVATE
// (tab[4][128], 4 KiB LDS). Within a wave, ds_write -> ds_read is ordered by
// compiler-inserted lgkmcnt waits (wave64 lockstep), so no barrier -- and no
// "s_waitcnt vmcnt(0) lgkmcnt(0)" drain on every block start. The 4 HBM
// dwordx4 loads are issued FIRST so streaming begins before the table build.

#define ELEMS_PER_BLOCK 4096

typedef float v4f __attribute__((ext_vector_type(4)));  // native clang vector:
// __builtin_nontemporal_* requires scalar/vector-of-scalar pointee.

__global__ __launch_bounds__(256) void LinearSpline_kernel(
    const float* __restrict__ x,
    const float* __restrict__ coef,
    const float* __restrict__ scal,
    const int*   __restrict__ zk,
    float*       __restrict__ out)
{
    __shared__ float2 tab[4][128];   // per-wave private copy -> no barrier needed

    const long long base = (long long)blockIdx.x * ELEMS_PER_BLOCK;
    const int c = (int)((base >> 16) & 63);  // channel = (idx / 65536) % 64

    const int wid  = (int)(threadIdx.x >> 6);   // wave id 0..3
    const int lane = (int)(threadIdx.x & 63);

    const v4f* __restrict__ xin = (const v4f*)(x + base);
    v4f*       __restrict__ xo  = (v4f*)(out + base);

    // ---- 1) issue all HBM reads up front (16 KiB/block in flight) ----------
    v4f v0 = __builtin_nontemporal_load(&xin[0 * 256 + threadIdx.x]);
    v4f v1 = __builtin_nontemporal_load(&xin[1 * 256 + threadIdx.x]);
    v4f v2 = __builtin_nontemporal_load(&xin[2 * 256 + threadIdx.x]);
    v4f v3 = __builtin_nontemporal_load(&xin[3 * 256 + threadIdx.x]);

    // ---- 2) wave-local table build (hides under the loads above) -----------
    const float sc  = scal[c];        // block-uniform -> scalar load
    const float rs  = 1.0f / sc;
    const float s16 = sc * 16.0f;     // fold 1/GRID into the scale
    const int   tb  = zk[c] - 64;     // table base = c*129

    {
        const float a0 = coef[tb + lane];
        const float a1 = coef[tb + lane + 1];
        tab[wid][lane] = make_float2((a0 - 0.03125f) * rs, (a1 - a0) * rs);
        const float b0 = coef[tb + lane + 64];
        const float b1 = coef[tb + lane + 65];
        tab[wid][lane + 64] = make_float2((b0 - 0.03125f) * rs, (b1 - b0) * rs);
    }
    // no __syncthreads(): each wave only reads its own tab[wid] copy; the
    // compiler orders the ds_write -> ds_read pair via lgkmcnt.

    auto ev = [&](float xv) -> float {
        const float t  = xv * s16;                       // xg / GRID (exact)
        const float tc = fminf(fmaxf(t, -64.0f), 63.0f); // clamp in scaled domain
        const float fl = floorf(tc);
        const float fr = t - fl;                         // fracs from UNclamped xg
        const int   k  = (int)fl + 64;                   // 0..127
        const float2 e = tab[wid][k];
        return fmaf(fr, e.y, e.x);
    };

    // ---- 3) compute + stream out -------------------------------------------
    v4f r0; r0.x = ev(v0.x); r0.y = ev(v0.y); r0.z = ev(v0.z); r0.w = ev(v0.w);
    __builtin_nontemporal_store(r0, &xo[0 * 256 + threadIdx.x]);
    v4f r1; r1.x = ev(v1.x); r1.y = ev(v1.y); r1.z = ev(v1.z); r1.w = ev(v1.w);
    __builtin_nontemporal_store(r1, &xo[1 * 256 + threadIdx.x]);
    v4f r2; r2.x = ev(v2.x); r2.y = ev(v2.y); r2.z = ev(v2.z); r2.w = ev(v2.w);
    __builtin_nontemporal_store(r2, &xo[2 * 256 + threadIdx.x]);
    v4f r3; r3.x = ev(v3.x); r3.y = ev(v3.y); r3.z = ev(v3.z); r3.w = ev(v3.w);
    __builtin_nontemporal_store(r3, &xo[3 * 256 + threadIdx.x]);
}

extern "C" void kernel_launch(void* const* d_in, const int* in_sizes, int n_in,
                              void* d_out, int out_size, void* d_ws, size_t ws_size,
                              hipStream_t stream) {
    const float* x    = (const float*)d_in[0];
    const float* coef = (const float*)d_in[1];
    const float* scal = (const float*)d_in[2];
    const int*   zk   = (const int*)d_in[3];
    float*       out  = (float*)d_out;

    const int blocks = out_size / ELEMS_PER_BLOCK;  // 67108864 / 4096 = 16384
    LinearSpline_kernel<<<blocks, 256, 0, stream>>>(x, coef, scal, zk, out);
}